// Round 3
// baseline (701.774 us; speedup 1.0000x reference)
//
#include <hip/hip_runtime.h>
#include <hip/hip_bf16.h>
#include <stdint.h>

typedef unsigned short bf16_t;
typedef __attribute__((ext_vector_type(8))) short short8;
typedef __attribute__((ext_vector_type(4))) float f32x4;

#define BM 128
#define BN 128
#define BK 32

__device__ __forceinline__ bf16_t f2b(float f) {
    union { float f; uint32_t u; } v; v.f = f;
    uint32_t u = v.u;
    return (bf16_t)((u + 0x7FFFu + ((u >> 16) & 1u)) >> 16);
}

__device__ __forceinline__ float b2f(bf16_t h) {
    union { uint32_t u; float f; } v; v.u = ((uint32_t)h) << 16;
    return v.f;
}

__global__ __launch_bounds__(256) void cvt_f32_bf16(const float* __restrict__ in,
                                                    bf16_t* __restrict__ out, int n4) {
    int i = blockIdx.x * blockDim.x + threadIdx.x;
    if (i >= n4) return;
    float4 f = ((const float4*)in)[i];
    ushort4 o;
    o.x = f2b(f.x); o.y = f2b(f.y); o.z = f2b(f.z); o.w = f2b(f.w);
    ((ushort4*)out)[i] = o;
}

__device__ __forceinline__ void lds_dma16(const void* g, void* l) {
    __builtin_amdgcn_global_load_lds(
        (const __attribute__((address_space(1))) void*)g,
        (__attribute__((address_space(3))) void*)l, 16, 0, 0);
}

// C = A (M x K row-major, lda) * B^T (B stored N x K row-major, ldb) + epilogue
// MODE 0: out bf16 row-major, val=(acc+bias[col])*scale          (Q/K proj)
// MODE 2: out bf16 transposed Vt[b][col][s], val=acc+bias[col]   (V proj)
template <int MODE>
__global__ __launch_bounds__(256)
void gemm_bt(const bf16_t* __restrict__ Ag, int lda,
             const bf16_t* __restrict__ Bg, int ldb,
             const float* __restrict__ bias,
             void* __restrict__ outp, int ldo,
             int K, float scale)
{
    __shared__ bf16_t lsA[BM * BK];
    __shared__ bf16_t lsB[BN * BK];

    const int tid  = threadIdx.x;
    const int lane = tid & 63;
    const int w    = tid >> 6;
    const int wm   = w & 1, wn = w >> 1;
    const int ll   = lane & 15;
    const int quad = lane >> 4;

    const int m0 = blockIdx.y * BM;
    const int n0 = blockIdx.x * BN;

    const bf16_t* A = Ag;
    const bf16_t* B = Bg;

    f32x4 acc[4][4];
#pragma unroll
    for (int i = 0; i < 4; i++)
#pragma unroll
        for (int j = 0; j < 4; j++) acc[i][j] = (f32x4){0.f, 0.f, 0.f, 0.f};

    for (int k0 = 0; k0 < K; k0 += BK) {
#pragma unroll
        for (int c = 0; c < 2; ++c) {
            const int base = (c * 4 + w) * 64;
            const int idx  = base + lane;
            const int row  = idx >> 2;
            const int kc   = (idx & 3) << 3;
            lds_dma16(A + (size_t)(m0 + row) * lda + k0 + kc, (char*)lsA + base * 16);
            lds_dma16(B + (size_t)(n0 + row) * ldb + k0 + kc, (char*)lsB + base * 16);
        }
        __syncthreads();

        short8 af[4], bf[4];
#pragma unroll
        for (int i = 0; i < 4; i++) {
            af[i] = *(const short8*)(lsA + (wm * 64 + i * 16 + ll) * BK + quad * 8);
            bf[i] = *(const short8*)(lsB + (wn * 64 + i * 16 + ll) * BK + quad * 8);
        }
#pragma unroll
        for (int i = 0; i < 4; i++)
#pragma unroll
            for (int j = 0; j < 4; j++)
                acc[i][j] = __builtin_amdgcn_mfma_f32_16x16x32_bf16(af[i], bf[j], acc[i][j], 0, 0, 0);
        __syncthreads();
    }

#pragma unroll
    for (int i = 0; i < 4; i++) {
#pragma unroll
        for (int j = 0; j < 4; j++) {
            const int col  = n0 + wn * 64 + j * 16 + ll;
            const int rowb = m0 + wm * 64 + i * 16 + quad * 4;
            f32x4 a = acc[i][j];
            if (MODE == 0) {
                const float bv = bias[col];
                bf16_t* o = (bf16_t*)outp;
#pragma unroll
                for (int r = 0; r < 4; r++)
                    o[(size_t)(rowb + r) * ldo + col] = f2b((a[r] + bv) * scale);
            } else { // MODE 2: Vt[b][col][s]
                const float bv = bias[col];
                bf16_t* o = (bf16_t*)outp;
                const int b = rowb >> 12;
                const int s = rowb & 4095;
                ushort4 pk;
                pk.x = f2b(a[0] + bv);
                pk.y = f2b(a[1] + bv);
                pk.z = f2b(a[2] + bv);
                pk.w = f2b(a[3] + bv);
                *(ushort4*)(o + ((size_t)b * 512 + col) * 4096 + s) = pk;
            }
        }
    }
}

// ---------------- fused sigmoid attention, streaming K/V ----------------
// grid (64, 4): x = q-tile of 64 rows, y = batch. 512 threads, 8 waves, 1 block/CU.
// Q: [z][4096][512] bf16 (pre-scaled 1/sqrt(D)), K same, Vt: [z][512][4096] bf16,
// biasb: [4096][4096] bf16. out: fp32 [z][4096][512].
// K and V are loaded straight to VGPR MFMA B-fragments (no LDS, no barriers);
// only the P transpose (C-layout -> A-layout) round-trips LDS, double-buffered,
// giving exactly ONE __syncthreads per 128-wide KV phase.
__global__ __launch_bounds__(512, 2)
void attn_fused(const bf16_t* __restrict__ Qg, const bf16_t* __restrict__ Kg,
                const bf16_t* __restrict__ Vtg, const bf16_t* __restrict__ biasb,
                float* __restrict__ outg)
{
    __shared__ __align__(16) bf16_t lsQ[32768];      // [dchunk=16][row=64][32 d]  64 KB
    __shared__ __align__(16) bf16_t lsP[2][64 * 136]; // P tile dbuf, padded ld=136

    const int tid  = threadIdx.x;
    const int lane = tid & 63;
    const int w    = tid >> 6;   // 0..7
    const int ll   = lane & 15;
    const int quad = lane >> 4;
    const int wm   = w & 1;      // row half (32 rows)
    const int wn   = w >> 1;     // 0..3: QK col group (32), PV col group (128)

    const int q0 = blockIdx.x * 64;
    const int z  = blockIdx.y;

    const bf16_t* Qz = Qg + (size_t)z * 4096 * 512;
    const bf16_t* Kz = Kg + (size_t)z * 4096 * 512;
    const bf16_t* Vz = Vtg + (size_t)z * 512 * 4096;

    // ---- stage Q once: [dchunk16][row64][32d]; chunk index == slot, 8 rounds ----
#pragma unroll
    for (int c = 0; c < 8; c++) {
        const int slot = c * 512 + tid;
        const int goff = (q0 + ((slot >> 2) & 63)) * 512 + (slot >> 8) * 32 + (slot & 3) * 8;
        lds_dma16(Qz + goff, (char*)lsQ + (c * 512 + w * 64) * 16);
    }
    __syncthreads();

    f32x4 accO[2][8];
#pragma unroll
    for (int i = 0; i < 2; i++)
#pragma unroll
        for (int j = 0; j < 8; j++) accO[i][j] = (f32x4){0.f, 0.f, 0.f, 0.f};

    for (int n0 = 0; n0 < 4096; n0 += 128) {
        const int ph = (n0 >> 7) & 1;
        bf16_t* P = lsP[ph];

        // ---- S = Q K^T : K fragments straight from global, Q from LDS ----
        f32x4 accS[2][2];
#pragma unroll
        for (int i = 0; i < 2; i++)
#pragma unroll
            for (int j = 0; j < 2; j++) accS[i][j] = (f32x4){0.f, 0.f, 0.f, 0.f};

        const bf16_t* Kb_ = Kz + (size_t)(n0 + wn * 32) * 512;
#pragma unroll
        for (int dc = 0; dc < 16; dc++) {
            short8 bK0 = *(const short8*)(Kb_ + (size_t)ll * 512 + dc * 32 + quad * 8);
            short8 bK1 = *(const short8*)(Kb_ + (size_t)(16 + ll) * 512 + dc * 32 + quad * 8);
            short8 aQ0 = *(const short8*)(lsQ + dc * 2048 + (wm * 32 + ll) * 32 + quad * 8);
            short8 aQ1 = *(const short8*)(lsQ + dc * 2048 + (wm * 32 + 16 + ll) * 32 + quad * 8);
            accS[0][0] = __builtin_amdgcn_mfma_f32_16x16x32_bf16(aQ0, bK0, accS[0][0], 0, 0, 0);
            accS[0][1] = __builtin_amdgcn_mfma_f32_16x16x32_bf16(aQ0, bK1, accS[0][1], 0, 0, 0);
            accS[1][0] = __builtin_amdgcn_mfma_f32_16x16x32_bf16(aQ1, bK0, accS[1][0], 0, 0, 0);
            accS[1][1] = __builtin_amdgcn_mfma_f32_16x16x32_bf16(aQ1, bK1, accS[1][1], 0, 0, 0);
        }

        // ---- sigmoid(S + bias) -> P (bf16, LDS dbuf) ----
#pragma unroll
        for (int mi = 0; mi < 2; mi++) {
#pragma unroll
            for (int nj = 0; nj < 2; nj++) {
                const int colL = wn * 32 + nj * 16 + ll;
#pragma unroll
                for (int r = 0; r < 4; r++) {
                    const int row = wm * 32 + mi * 16 + quad * 4 + r;
                    const float v = accS[mi][nj][r] +
                                    b2f(biasb[(size_t)(q0 + row) * 4096 + n0 + colL]);
                    P[row * 136 + colL] = f2b(__builtin_amdgcn_rcpf(1.f + __expf(-v)));
                }
            }
        }
        __syncthreads();  // the ONLY barrier per phase: P visible to all waves

        // ---- O += P * V : V fragments straight from global, P from LDS ----
        const bf16_t* Vb_ = Vz + (size_t)(wn * 128) * 4096 + n0;
#pragma unroll
        for (int t = 0; t < 4; t++) {
            short8 aP0 = *(const short8*)(P + (wm * 32 + ll) * 136 + t * 32 + quad * 8);
            short8 aP1 = *(const short8*)(P + (wm * 32 + 16 + ll) * 136 + t * 32 + quad * 8);
#pragma unroll
            for (int nj = 0; nj < 8; nj++) {
                short8 bV = *(const short8*)(Vb_ + (size_t)(nj * 16 + ll) * 4096 + t * 32 + quad * 8);
                accO[0][nj] = __builtin_amdgcn_mfma_f32_16x16x32_bf16(aP0, bV, accO[0][nj], 0, 0, 0);
                accO[1][nj] = __builtin_amdgcn_mfma_f32_16x16x32_bf16(aP1, bV, accO[1][nj], 0, 0, 0);
            }
        }
    }

    // ---- epilogue: out[z][q0 + wm*32 + mi*16 + quad*4 + r][wn*128 + nj*16 + ll] ----
#pragma unroll
    for (int nj = 0; nj < 8; nj++) {
        const int col = wn * 128 + nj * 16 + ll;
#pragma unroll
        for (int mi = 0; mi < 2; mi++) {
#pragma unroll
            for (int r = 0; r < 4; r++) {
                const int row = q0 + wm * 32 + mi * 16 + quad * 4 + r;
                outg[((size_t)z * 4096 + row) * 512 + col] = accO[mi][nj][r];
            }
        }
    }
}

extern "C" void kernel_launch(void* const* d_in, const int* in_sizes, int n_in,
                              void* d_out, int out_size, void* d_ws, size_t ws_size,
                              hipStream_t stream) {
    (void)in_sizes; (void)n_in; (void)out_size; (void)ws_size;
    const float* x    = (const float*)d_in[0];
    const float* bias = (const float*)d_in[1];
    const float* Wq_w = (const float*)d_in[2];
    const float* Wq_b = (const float*)d_in[3];
    const float* Wk_w = (const float*)d_in[4];
    const float* Wk_b = (const float*)d_in[5];
    const float* Wv_w = (const float*)d_in[6];
    const float* Wv_b = (const float*)d_in[7];
    float* out = (float*)d_out;

    // workspace layout (bf16 elements)
    bf16_t* Xb = (bf16_t*)d_ws;                    // 16384 x 512
    bf16_t* Wb = Xb + (size_t)16384 * 512;         // 3 x 512 x 512
    bf16_t* Qb = Wb + (size_t)3 * 512 * 512;       // 16384 x 512 (pre-scaled by 1/sqrt(D))
    bf16_t* Kb = Qb + (size_t)16384 * 512;         // 16384 x 512
    bf16_t* Vt = Kb + (size_t)16384 * 512;         // 4 x 512 x 4096 (transposed V)
    bf16_t* Bb = Vt + (size_t)16384 * 512;         // 4096 x 4096 bias in bf16
    // total ~98 MB

    cvt_f32_bf16<<<8192, 256, 0, stream>>>(x, Xb, 2097152);
    cvt_f32_bf16<<<256, 256, 0, stream>>>(Wq_w, Wb, 65536);
    cvt_f32_bf16<<<256, 256, 0, stream>>>(Wk_w, Wb + 262144, 65536);
    cvt_f32_bf16<<<256, 256, 0, stream>>>(Wv_w, Wb + 524288, 65536);
    cvt_f32_bf16<<<16384, 256, 0, stream>>>(bias, Bb, 4194304);

    const float inv = 0.044194173824159216f;  // 1/sqrt(512)

    // projections: M=16384, N=512, K=512
    gemm_bt<0><<<dim3(4, 128), 256, 0, stream>>>(Xb, 512, Wb, 512,
                                                 Wq_b, Qb, 512, 512, inv);
    gemm_bt<0><<<dim3(4, 128), 256, 0, stream>>>(Xb, 512, Wb + 262144, 512,
                                                 Wk_b, Kb, 512, 512, 1.0f);
    gemm_bt<2><<<dim3(4, 128), 256, 0, stream>>>(Xb, 512, Wb + 524288, 512,
                                                 Wv_b, Vt, 0, 512, 1.0f);

    // fused sigmoid attention: scores + sigmoid + PV, streaming K/V to registers
    attn_fused<<<dim3(64, 4), 512, 0, stream>>>(Qb, Kb, Vt, Bb, out);
}

// Round 4
// 497.918 us; speedup vs baseline: 1.4094x; 1.4094x over previous
//
#include <hip/hip_runtime.h>
#include <hip/hip_bf16.h>
#include <stdint.h>

typedef unsigned short bf16_t;
typedef __attribute__((ext_vector_type(8))) short short8;
typedef __attribute__((ext_vector_type(4))) float f32x4;

__device__ __forceinline__ bf16_t f2b(float f) {
    union { float f; uint32_t u; } v; v.f = f;
    uint32_t u = v.u;
    return (bf16_t)((u + 0x7FFFu + ((u >> 16) & 1u)) >> 16);
}

__global__ __launch_bounds__(256) void cvt_f32_bf16(const float* __restrict__ in,
                                                    bf16_t* __restrict__ out, int n4) {
    int i = blockIdx.x * blockDim.x + threadIdx.x;
    if (i >= n4) return;
    float4 f = ((const float4*)in)[i];
    ushort4 o;
    o.x = f2b(f.x); o.y = f2b(f.y); o.z = f2b(f.z); o.w = f2b(f.w);
    ((ushort4*)out)[i] = o;
}

__device__ __forceinline__ void lds_dma16(const void* g, void* l) {
    __builtin_amdgcn_global_load_lds(
        (const __attribute__((address_space(1))) void*)g,
        (__attribute__((address_space(3))) void*)l, 16, 0, 0);
}

// ---------- projections: Q/K/V in one launch (grid.z = 0,1,2) ----------
// Y = X (16384x512) * W_z^T (512x512) + b_z; z=0: *1/sqrt(D) -> Qb
// z=1 -> Kb; z=2 -> Vt transposed [batch][d][s]
__global__ __launch_bounds__(256)
void proj_all(const bf16_t* __restrict__ Xb, const bf16_t* __restrict__ Wb,
              const float* __restrict__ qb, const float* __restrict__ kb,
              const float* __restrict__ vb,
              bf16_t* __restrict__ Qb, bf16_t* __restrict__ Kb,
              bf16_t* __restrict__ Vt)
{
    __shared__ bf16_t lsA[128 * 32];
    __shared__ bf16_t lsB[128 * 32];

    const int tid  = threadIdx.x;
    const int lane = tid & 63;
    const int w    = tid >> 6;
    const int wm   = w & 1, wn = w >> 1;
    const int ll   = lane & 15;
    const int quad = lane >> 4;

    const int m0 = blockIdx.y * 128;
    const int n0 = blockIdx.x * 128;
    const int z  = blockIdx.z;

    const bf16_t* A = Xb;
    const bf16_t* B = Wb + z * 262144;

    f32x4 acc[4][4];
#pragma unroll
    for (int i = 0; i < 4; i++)
#pragma unroll
        for (int j = 0; j < 4; j++) acc[i][j] = (f32x4){0.f, 0.f, 0.f, 0.f};

    for (int k0 = 0; k0 < 512; k0 += 32) {
#pragma unroll
        for (int c = 0; c < 2; ++c) {
            const int base = (c * 4 + w) * 64;
            const int idx  = base + lane;
            const int row  = idx >> 2;
            const int kc   = (idx & 3) << 3;
            lds_dma16(A + (size_t)(m0 + row) * 512 + k0 + kc, (char*)lsA + base * 16);
            lds_dma16(B + (size_t)(n0 + row) * 512 + k0 + kc, (char*)lsB + base * 16);
        }
        __syncthreads();

        short8 af[4], bf[4];
#pragma unroll
        for (int i = 0; i < 4; i++) {
            af[i] = *(const short8*)(lsA + (wm * 64 + i * 16 + ll) * 32 + quad * 8);
            bf[i] = *(const short8*)(lsB + (wn * 64 + i * 16 + ll) * 32 + quad * 8);
        }
#pragma unroll
        for (int i = 0; i < 4; i++)
#pragma unroll
            for (int j = 0; j < 4; j++)
                acc[i][j] = __builtin_amdgcn_mfma_f32_16x16x32_bf16(af[i], bf[j], acc[i][j], 0, 0, 0);
        __syncthreads();
    }

    const float inv = 0.044194173824159216f;  // 1/sqrt(512)
#pragma unroll
    for (int i = 0; i < 4; i++) {
#pragma unroll
        for (int j = 0; j < 4; j++) {
            const int col  = n0 + wn * 64 + j * 16 + ll;
            const int rowb = m0 + wm * 64 + i * 16 + quad * 4;
            f32x4 a = acc[i][j];
            if (z == 0) {
                const float bv = qb[col];
#pragma unroll
                for (int r = 0; r < 4; r++)
                    Qb[(size_t)(rowb + r) * 512 + col] = f2b((a[r] + bv) * inv);
            } else if (z == 1) {
                const float bv = kb[col];
#pragma unroll
                for (int r = 0; r < 4; r++)
                    Kb[(size_t)(rowb + r) * 512 + col] = f2b(a[r] + bv);
            } else {  // V, transposed store Vt[b][col][s]
                const float bv = vb[col];
                const int b = rowb >> 12;
                const int s = rowb & 4095;
                ushort4 pk;
                pk.x = f2b(a[0] + bv);
                pk.y = f2b(a[1] + bv);
                pk.z = f2b(a[2] + bv);
                pk.w = f2b(a[3] + bv);
                *(ushort4*)(Vt + ((size_t)b * 512 + col) * 4096 + s) = pk;
            }
        }
    }
}

// ---------- scores: P = sigmoid(Q K^T + bias), bf16 out, cheap epilogue ----------
__global__ __launch_bounds__(256)
void scores_sig(const bf16_t* __restrict__ Qb, const bf16_t* __restrict__ Kb,
                const float* __restrict__ bias, bf16_t* __restrict__ P)
{
    __shared__ bf16_t lsA[128 * 32];
    __shared__ bf16_t lsB[128 * 32];

    const int tid  = threadIdx.x;
    const int lane = tid & 63;
    const int w    = tid >> 6;
    const int wm   = w & 1, wn = w >> 1;
    const int ll   = lane & 15;
    const int quad = lane >> 4;

    const int m0 = blockIdx.y * 128;
    const int n0 = blockIdx.x * 128;
    const int z  = blockIdx.z;

    const bf16_t* A = Qb + (size_t)z * 2097152;
    const bf16_t* B = Kb + (size_t)z * 2097152;
    bf16_t* out = P + (size_t)z * 16777216;

    f32x4 acc[4][4];
#pragma unroll
    for (int i = 0; i < 4; i++)
#pragma unroll
        for (int j = 0; j < 4; j++) acc[i][j] = (f32x4){0.f, 0.f, 0.f, 0.f};

    for (int k0 = 0; k0 < 512; k0 += 32) {
#pragma unroll
        for (int c = 0; c < 2; ++c) {
            const int base = (c * 4 + w) * 64;
            const int idx  = base + lane;
            const int row  = idx >> 2;
            const int kc   = (idx & 3) << 3;
            lds_dma16(A + (size_t)(m0 + row) * 512 + k0 + kc, (char*)lsA + base * 16);
            lds_dma16(B + (size_t)(n0 + row) * 512 + k0 + kc, (char*)lsB + base * 16);
        }
        __syncthreads();

        short8 af[4], bf[4];
#pragma unroll
        for (int i = 0; i < 4; i++) {
            af[i] = *(const short8*)(lsA + (wm * 64 + i * 16 + ll) * 32 + quad * 8);
            bf[i] = *(const short8*)(lsB + (wn * 64 + i * 16 + ll) * 32 + quad * 8);
        }
#pragma unroll
        for (int i = 0; i < 4; i++)
#pragma unroll
            for (int j = 0; j < 4; j++)
                acc[i][j] = __builtin_amdgcn_mfma_f32_16x16x32_bf16(af[i], bf[j], acc[i][j], 0, 0, 0);
        __syncthreads();
    }

    // cheap sigmoid epilogue: fp32 bias (L3-resident), __expf + rcp, TRUNCATED bf16 pack
#pragma unroll
    for (int i = 0; i < 4; i++) {
#pragma unroll
        for (int j = 0; j < 4; j++) {
            const int col  = n0 + wn * 64 + j * 16 + ll;
            const int rowb = m0 + wm * 64 + i * 16 + quad * 4;
            f32x4 a = acc[i][j];
#pragma unroll
            for (int r = 0; r < 4; r++) {
                const int row = rowb + r;
                const float v = a[r] + bias[(size_t)row * 4096 + col];
                const float p = __builtin_amdgcn_rcpf(1.f + __expf(-v));
                out[(size_t)row * 4096 + col] = (bf16_t)(__float_as_uint(p) >> 16);
            }
        }
    }
}

// ---------- PV: out = P * Vt^T, 128x64 tile (1024 blocks -> 4 blocks/CU) ----------
__global__ __launch_bounds__(256)
void pv_gemm(const bf16_t* __restrict__ P, const bf16_t* __restrict__ Vt,
             float* __restrict__ outg)
{
    __shared__ bf16_t lsA[128 * 32];
    __shared__ bf16_t lsB[64 * 32];

    const int tid  = threadIdx.x;
    const int lane = tid & 63;
    const int w    = tid >> 6;
    const int wm   = w & 1, wn = w >> 1;
    const int ll   = lane & 15;
    const int quad = lane >> 4;

    const int m0 = blockIdx.y * 128;
    const int n0 = blockIdx.x * 64;
    const int z  = blockIdx.z;

    const bf16_t* A = P + (size_t)z * 16777216;   // [4096][4096]
    const bf16_t* B = Vt + (size_t)z * 2097152;   // [512][4096]
    float* out = outg + (size_t)z * 2097152;

    f32x4 acc[4][2];
#pragma unroll
    for (int i = 0; i < 4; i++)
#pragma unroll
        for (int j = 0; j < 2; j++) acc[i][j] = (f32x4){0.f, 0.f, 0.f, 0.f};

    for (int k0 = 0; k0 < 4096; k0 += 32) {
        // stage A (512 chunks) + B (256 chunks) = 3 rounds x 256 threads
#pragma unroll
        for (int c = 0; c < 3; ++c) {
            const int base = (c * 4 + w) * 64;   // 0..704, wave-uniform
            const int slot = base + lane;
            if (slot < 512) {
                const int row = slot >> 2;
                const int kc  = (slot & 3) << 3;
                lds_dma16(A + (size_t)(m0 + row) * 4096 + k0 + kc, (char*)lsA + base * 16);
            } else {
                const int s2  = slot - 512;
                const int row = s2 >> 2;
                const int kc  = (s2 & 3) << 3;
                lds_dma16(B + (size_t)(n0 + row) * 4096 + k0 + kc,
                          (char*)lsB + (base - 512) * 16);
            }
        }
        __syncthreads();

        short8 af[4], bf[2];
#pragma unroll
        for (int i = 0; i < 4; i++)
            af[i] = *(const short8*)(lsA + (wm * 64 + i * 16 + ll) * 32 + quad * 8);
#pragma unroll
        for (int j = 0; j < 2; j++)
            bf[j] = *(const short8*)(lsB + (wn * 32 + j * 16 + ll) * 32 + quad * 8);
#pragma unroll
        for (int i = 0; i < 4; i++)
#pragma unroll
            for (int j = 0; j < 2; j++)
                acc[i][j] = __builtin_amdgcn_mfma_f32_16x16x32_bf16(af[i], bf[j], acc[i][j], 0, 0, 0);
        __syncthreads();
    }

#pragma unroll
    for (int i = 0; i < 4; i++) {
#pragma unroll
        for (int j = 0; j < 2; j++) {
            const int col  = n0 + wn * 32 + j * 16 + ll;
            const int rowb = m0 + wm * 64 + i * 16 + quad * 4;
            f32x4 a = acc[i][j];
#pragma unroll
            for (int r = 0; r < 4; r++)
                out[(size_t)(rowb + r) * 512 + col] = a[r];
        }
    }
}

extern "C" void kernel_launch(void* const* d_in, const int* in_sizes, int n_in,
                              void* d_out, int out_size, void* d_ws, size_t ws_size,
                              hipStream_t stream) {
    (void)in_sizes; (void)n_in; (void)out_size; (void)ws_size;
    const float* x    = (const float*)d_in[0];
    const float* bias = (const float*)d_in[1];
    const float* Wq_w = (const float*)d_in[2];
    const float* Wq_b = (const float*)d_in[3];
    const float* Wk_w = (const float*)d_in[4];
    const float* Wk_b = (const float*)d_in[5];
    const float* Wv_w = (const float*)d_in[6];
    const float* Wv_b = (const float*)d_in[7];
    float* out = (float*)d_out;

    // workspace layout (bf16 elements) — identical footprint to round 1 (proven)
    bf16_t* Xb = (bf16_t*)d_ws;                    // 16384 x 512
    bf16_t* Wb = Xb + (size_t)16384 * 512;         // 3 x 512 x 512
    bf16_t* Qb = Wb + (size_t)3 * 512 * 512;       // 16384 x 512 (pre-scaled 1/sqrt(D))
    bf16_t* Kb = Qb + (size_t)16384 * 512;         // 16384 x 512
    bf16_t* Vt = Kb + (size_t)16384 * 512;         // 4 x 512 x 4096 (transposed V)
    bf16_t* P  = Vt + (size_t)16384 * 512;         // 4 x 4096 x 4096

    cvt_f32_bf16<<<8192, 256, 0, stream>>>(x, Xb, 2097152);
    cvt_f32_bf16<<<256, 256, 0, stream>>>(Wq_w, Wb, 65536);
    cvt_f32_bf16<<<256, 256, 0, stream>>>(Wk_w, Wb + 262144, 65536);
    cvt_f32_bf16<<<256, 256, 0, stream>>>(Wv_w, Wb + 524288, 65536);

    // all three projections in one launch
    proj_all<<<dim3(4, 128, 3), 256, 0, stream>>>(Xb, Wb, Wq_b, Wk_b, Wv_b,
                                                  Qb, Kb, Vt);
    // scores + sigmoid (cheap epilogue)
    scores_sig<<<dim3(32, 32, 4), 256, 0, stream>>>(Qb, Kb, bias, P);
    // out = P * V, 128x64 tiles for 4 blocks/CU
    pv_gemm<<<dim3(8, 32, 4), 256, 0, stream>>>(P, Vt, out);
}

// Round 5
// 461.892 us; speedup vs baseline: 1.5193x; 1.0780x over previous
//
#include <hip/hip_runtime.h>
#include <hip/hip_bf16.h>
#include <stdint.h>

typedef unsigned short bf16_t;
typedef __attribute__((ext_vector_type(8))) short short8;
typedef __attribute__((ext_vector_type(4))) float f32x4;

__device__ __forceinline__ bf16_t f2b(float f) {
    union { float f; uint32_t u; } v; v.f = f;
    uint32_t u = v.u;
    return (bf16_t)((u + 0x7FFFu + ((u >> 16) & 1u)) >> 16);
}

__global__ __launch_bounds__(256) void cvt_f32_bf16(const float* __restrict__ in,
                                                    bf16_t* __restrict__ out, int n4) {
    int i = blockIdx.x * blockDim.x + threadIdx.x;
    if (i >= n4) return;
    float4 f = ((const float4*)in)[i];
    ushort4 o;
    o.x = f2b(f.x); o.y = f2b(f.y); o.z = f2b(f.z); o.w = f2b(f.w);
    ((ushort4*)out)[i] = o;
}

// three 512x512 weight matrices in one launch: 3 x 65536 float4 groups
__global__ __launch_bounds__(256) void cvt_w3(const float* __restrict__ a,
                                              const float* __restrict__ b,
                                              const float* __restrict__ c,
                                              bf16_t* __restrict__ out) {
    int i = blockIdx.x * blockDim.x + threadIdx.x;   // 0..196607
    const int which = i >> 16;
    const int idx   = i & 65535;
    const float* src = (which == 0) ? a : (which == 1) ? b : c;
    float4 f = ((const float4*)src)[idx];
    ushort4 o;
    o.x = f2b(f.x); o.y = f2b(f.y); o.z = f2b(f.z); o.w = f2b(f.w);
    ((ushort4*)out)[i] = o;
}

__device__ __forceinline__ void lds_dma16(const void* g, void* l) {
    __builtin_amdgcn_global_load_lds(
        (const __attribute__((address_space(1))) void*)g,
        (__attribute__((address_space(3))) void*)l, 16, 0, 0);
}

// ---------- projections: Q/K/V in one launch (grid.z = 0,1,2) ----------
__global__ __launch_bounds__(256)
void proj_all(const bf16_t* __restrict__ Xb, const bf16_t* __restrict__ Wb,
              const float* __restrict__ qb, const float* __restrict__ kb,
              const float* __restrict__ vb,
              bf16_t* __restrict__ Qb, bf16_t* __restrict__ Kb,
              bf16_t* __restrict__ Vt)
{
    __shared__ bf16_t lsA[128 * 32];
    __shared__ bf16_t lsB[128 * 32];

    const int tid  = threadIdx.x;
    const int lane = tid & 63;
    const int w    = tid >> 6;
    const int wm   = w & 1, wn = w >> 1;
    const int ll   = lane & 15;
    const int quad = lane >> 4;

    const int m0 = blockIdx.y * 128;
    const int n0 = blockIdx.x * 128;
    const int z  = blockIdx.z;

    const bf16_t* A = Xb;
    const bf16_t* B = Wb + z * 262144;

    f32x4 acc[4][4];
#pragma unroll
    for (int i = 0; i < 4; i++)
#pragma unroll
        for (int j = 0; j < 4; j++) acc[i][j] = (f32x4){0.f, 0.f, 0.f, 0.f};

    for (int k0 = 0; k0 < 512; k0 += 32) {
#pragma unroll
        for (int c = 0; c < 2; ++c) {
            const int base = (c * 4 + w) * 64;
            const int idx  = base + lane;
            const int row  = idx >> 2;
            const int kc   = (idx & 3) << 3;
            lds_dma16(A + (size_t)(m0 + row) * 512 + k0 + kc, (char*)lsA + base * 16);
            lds_dma16(B + (size_t)(n0 + row) * 512 + k0 + kc, (char*)lsB + base * 16);
        }
        __syncthreads();

        short8 af[4], bf[4];
#pragma unroll
        for (int i = 0; i < 4; i++) {
            af[i] = *(const short8*)(lsA + (wm * 64 + i * 16 + ll) * 32 + quad * 8);
            bf[i] = *(const short8*)(lsB + (wn * 64 + i * 16 + ll) * 32 + quad * 8);
        }
#pragma unroll
        for (int i = 0; i < 4; i++)
#pragma unroll
            for (int j = 0; j < 4; j++)
                acc[i][j] = __builtin_amdgcn_mfma_f32_16x16x32_bf16(af[i], bf[j], acc[i][j], 0, 0, 0);
        __syncthreads();
    }

    const float inv = 0.044194173824159216f;  // 1/sqrt(512)
#pragma unroll
    for (int i = 0; i < 4; i++) {
#pragma unroll
        for (int j = 0; j < 4; j++) {
            const int col  = n0 + wn * 64 + j * 16 + ll;
            const int rowb = m0 + wm * 64 + i * 16 + quad * 4;
            f32x4 a = acc[i][j];
            if (z == 0) {
                const float bv = qb[col];
#pragma unroll
                for (int r = 0; r < 4; r++)
                    Qb[(size_t)(rowb + r) * 512 + col] = f2b((a[r] + bv) * inv);
            } else if (z == 1) {
                const float bv = kb[col];
#pragma unroll
                for (int r = 0; r < 4; r++)
                    Kb[(size_t)(rowb + r) * 512 + col] = f2b(a[r] + bv);
            } else {  // V, transposed store Vt[b][col][s]
                const float bv = vb[col];
                const int b = rowb >> 12;
                const int s = rowb & 4095;
                ushort4 pk;
                pk.x = f2b(a[0] + bv);
                pk.y = f2b(a[1] + bv);
                pk.z = f2b(a[2] + bv);
                pk.w = f2b(a[3] + bv);
                *(ushort4*)(Vt + ((size_t)b * 512 + col) * 4096 + s) = pk;
            }
        }
    }
}

// ---------- scores: P = sigmoid(Q K^T + bias), batch on blockIdx.x ----------
// grid (4, 32, 32): x = batch (4 siblings share the bias tile via L2/L3),
// y = n-tile, z = m-tile.
__global__ __launch_bounds__(256)
void scores_sig(const bf16_t* __restrict__ Qb, const bf16_t* __restrict__ Kb,
                const float* __restrict__ bias, bf16_t* __restrict__ P)
{
    __shared__ bf16_t lsA[128 * 32];
    __shared__ bf16_t lsB[128 * 32];

    const int tid  = threadIdx.x;
    const int lane = tid & 63;
    const int w    = tid >> 6;
    const int wm   = w & 1, wn = w >> 1;
    const int ll   = lane & 15;
    const int quad = lane >> 4;

    const int z  = blockIdx.x;
    const int n0 = blockIdx.y * 128;
    const int m0 = blockIdx.z * 128;

    const bf16_t* A = Qb + (size_t)z * 2097152;
    const bf16_t* B = Kb + (size_t)z * 2097152;
    bf16_t* out = P + (size_t)z * 16777216;

    f32x4 acc[4][4];
#pragma unroll
    for (int i = 0; i < 4; i++)
#pragma unroll
        for (int j = 0; j < 4; j++) acc[i][j] = (f32x4){0.f, 0.f, 0.f, 0.f};

    for (int k0 = 0; k0 < 512; k0 += 32) {
#pragma unroll
        for (int c = 0; c < 2; ++c) {
            const int base = (c * 4 + w) * 64;
            const int idx  = base + lane;
            const int row  = idx >> 2;
            const int kc   = (idx & 3) << 3;
            lds_dma16(A + (size_t)(m0 + row) * 512 + k0 + kc, (char*)lsA + base * 16);
            lds_dma16(B + (size_t)(n0 + row) * 512 + k0 + kc, (char*)lsB + base * 16);
        }
        __syncthreads();

        short8 af[4], bf[4];
#pragma unroll
        for (int i = 0; i < 4; i++) {
            af[i] = *(const short8*)(lsA + (wm * 64 + i * 16 + ll) * 32 + quad * 8);
            bf[i] = *(const short8*)(lsB + (wn * 64 + i * 16 + ll) * 32 + quad * 8);
        }
#pragma unroll
        for (int i = 0; i < 4; i++)
#pragma unroll
            for (int j = 0; j < 4; j++)
                acc[i][j] = __builtin_amdgcn_mfma_f32_16x16x32_bf16(af[i], bf[j], acc[i][j], 0, 0, 0);
        __syncthreads();
    }

    // cheap sigmoid epilogue: fp32 bias (shared by the 4 batch-siblings), truncated pack
#pragma unroll
    for (int i = 0; i < 4; i++) {
#pragma unroll
        for (int j = 0; j < 4; j++) {
            const int col  = n0 + wn * 64 + j * 16 + ll;
            const int rowb = m0 + wm * 64 + i * 16 + quad * 4;
            f32x4 a = acc[i][j];
#pragma unroll
            for (int r = 0; r < 4; r++) {
                const int row = rowb + r;
                const float v = a[r] + bias[(size_t)row * 4096 + col];
                const float p = __builtin_amdgcn_rcpf(1.f + __expf(-v));
                out[(size_t)row * 4096 + col] = (bf16_t)(__float_as_uint(p) >> 16);
            }
        }
    }
}

// ---------- PV: out = P * Vt^T, BM=64 BN=256, P re-read only 2x ----------
// grid (2, 64, 4), 256 threads, 4 waves: wave tile 64x64 (wn splits 256 cols).
__global__ __launch_bounds__(256)
void pv_gemm(const bf16_t* __restrict__ P, const bf16_t* __restrict__ Vt,
             float* __restrict__ outg)
{
    __shared__ bf16_t lsA[64 * 32];    // 4 KB
    __shared__ bf16_t lsB[256 * 32];   // 16 KB

    const int tid  = threadIdx.x;
    const int lane = tid & 63;
    const int w    = tid >> 6;
    const int wn   = w;            // 0..3: 64-col group
    const int ll   = lane & 15;
    const int quad = lane >> 4;

    const int n0 = blockIdx.x * 256;
    const int m0 = blockIdx.y * 64;
    const int z  = blockIdx.z;

    const bf16_t* A = P + (size_t)z * 16777216;   // [4096][4096]
    const bf16_t* B = Vt + (size_t)z * 2097152;   // [512][4096]
    float* out = outg + (size_t)z * 2097152;

    f32x4 acc[4][4];
#pragma unroll
    for (int i = 0; i < 4; i++)
#pragma unroll
        for (int j = 0; j < 4; j++) acc[i][j] = (f32x4){0.f, 0.f, 0.f, 0.f};

    for (int k0 = 0; k0 < 4096; k0 += 32) {
        // A: 64x32 = 256 chunks (1 round); B: 256x32 = 1024 chunks (4 rounds)
        {
            const int base = w * 64;
            const int slot = base + lane;
            const int row  = slot >> 2;
            const int kc   = (slot & 3) << 3;
            lds_dma16(A + (size_t)(m0 + row) * 4096 + k0 + kc, (char*)lsA + base * 16);
        }
#pragma unroll
        for (int c = 0; c < 4; ++c) {
            const int base = (c * 4 + w) * 64;
            const int slot = base + lane;
            const int row  = slot >> 2;
            const int kc   = (slot & 3) << 3;
            lds_dma16(B + (size_t)(n0 + row) * 4096 + k0 + kc, (char*)lsB + base * 16);
        }
        __syncthreads();

        short8 af[4], bf[4];
#pragma unroll
        for (int i = 0; i < 4; i++)
            af[i] = *(const short8*)(lsA + (i * 16 + ll) * 32 + quad * 8);
#pragma unroll
        for (int j = 0; j < 4; j++)
            bf[j] = *(const short8*)(lsB + (wn * 64 + j * 16 + ll) * 32 + quad * 8);
#pragma unroll
        for (int i = 0; i < 4; i++)
#pragma unroll
            for (int j = 0; j < 4; j++)
                acc[i][j] = __builtin_amdgcn_mfma_f32_16x16x32_bf16(af[i], bf[j], acc[i][j], 0, 0, 0);
        __syncthreads();
    }

#pragma unroll
    for (int i = 0; i < 4; i++) {
#pragma unroll
        for (int j = 0; j < 4; j++) {
            const int col  = n0 + wn * 64 + j * 16 + ll;
            const int rowb = m0 + i * 16 + quad * 4;
            f32x4 a = acc[i][j];
#pragma unroll
            for (int r = 0; r < 4; r++)
                out[(size_t)(rowb + r) * 512 + col] = a[r];
        }
    }
}

extern "C" void kernel_launch(void* const* d_in, const int* in_sizes, int n_in,
                              void* d_out, int out_size, void* d_ws, size_t ws_size,
                              hipStream_t stream) {
    (void)in_sizes; (void)n_in; (void)out_size; (void)ws_size;
    const float* x    = (const float*)d_in[0];
    const float* bias = (const float*)d_in[1];
    const float* Wq_w = (const float*)d_in[2];
    const float* Wq_b = (const float*)d_in[3];
    const float* Wk_w = (const float*)d_in[4];
    const float* Wk_b = (const float*)d_in[5];
    const float* Wv_w = (const float*)d_in[6];
    const float* Wv_b = (const float*)d_in[7];
    float* out = (float*)d_out;

    // workspace layout (bf16 elements)
    bf16_t* Xb = (bf16_t*)d_ws;                    // 16384 x 512
    bf16_t* Wb = Xb + (size_t)16384 * 512;         // 3 x 512 x 512
    bf16_t* Qb = Wb + (size_t)3 * 512 * 512;       // 16384 x 512 (pre-scaled 1/sqrt(D))
    bf16_t* Kb = Qb + (size_t)16384 * 512;         // 16384 x 512
    bf16_t* Vt = Kb + (size_t)16384 * 512;         // 4 x 512 x 4096 (transposed V)
    bf16_t* P  = Vt + (size_t)16384 * 512;         // 4 x 4096 x 4096

    cvt_f32_bf16<<<8192, 256, 0, stream>>>(x, Xb, 2097152);
    cvt_w3<<<768, 256, 0, stream>>>(Wq_w, Wk_w, Wv_w, Wb);

    // all three projections in one launch
    proj_all<<<dim3(4, 128, 3), 256, 0, stream>>>(Xb, Wb, Wq_b, Wk_b, Wv_b,
                                                  Qb, Kb, Vt);
    // scores + sigmoid; batch innermost so the 4 siblings share each bias tile
    scores_sig<<<dim3(4, 32, 32), 256, 0, stream>>>(Qb, Kb, bias, P);
    // out = P * V, 64x256 tiles: P re-read 2x, siblings adjacent
    pv_gemm<<<dim3(2, 64, 4), 256, 0, stream>>>(P, Vt, out);
}

// Round 6
// 435.447 us; speedup vs baseline: 1.6116x; 1.0607x over previous
//
#include <hip/hip_runtime.h>
#include <hip/hip_bf16.h>
#include <stdint.h>

typedef unsigned short bf16_t;
typedef __attribute__((ext_vector_type(8))) short short8;
typedef __attribute__((ext_vector_type(4))) float f32x4;

__device__ __forceinline__ bf16_t f2b(float f) {
    union { float f; uint32_t u; } v; v.f = f;
    uint32_t u = v.u;
    return (bf16_t)((u + 0x7FFFu + ((u >> 16) & 1u)) >> 16);
}

__global__ __launch_bounds__(256) void cvt_f32_bf16(const float* __restrict__ in,
                                                    bf16_t* __restrict__ out, int n4) {
    int i = blockIdx.x * blockDim.x + threadIdx.x;
    if (i >= n4) return;
    float4 f = ((const float4*)in)[i];
    ushort4 o;
    o.x = f2b(f.x); o.y = f2b(f.y); o.z = f2b(f.z); o.w = f2b(f.w);
    ((ushort4*)out)[i] = o;
}

// three 512x512 weight matrices in one launch
__global__ __launch_bounds__(256) void cvt_w3(const float* __restrict__ a,
                                              const float* __restrict__ b,
                                              const float* __restrict__ c,
                                              bf16_t* __restrict__ out) {
    int i = blockIdx.x * blockDim.x + threadIdx.x;   // 0..196607
    const int which = i >> 16;
    const int idx   = i & 65535;
    const float* src = (which == 0) ? a : (which == 1) ? b : c;
    float4 f = ((const float4*)src)[idx];
    ushort4 o;
    o.x = f2b(f.x); o.y = f2b(f.y); o.z = f2b(f.z); o.w = f2b(f.w);
    ((ushort4*)out)[i] = o;
}

__device__ __forceinline__ void lds_dma16(const void* g, void* l) {
    __builtin_amdgcn_global_load_lds(
        (const __attribute__((address_space(1))) void*)g,
        (__attribute__((address_space(3))) void*)l, 16, 0, 0);
}

// BK=64 swizzle contract: LDS[row][ch] holds global chunk (ch ^ (row&7));
// reader wanting global chunk g of row r reads LDS[r][g ^ (r&7)].

// ---------- projections: Q/K/V in one launch (grid.z = 0,1,2), BK=64 ----------
__global__ __launch_bounds__(256)
void proj_all(const bf16_t* __restrict__ Xb, const bf16_t* __restrict__ Wb,
              const float* __restrict__ qb, const float* __restrict__ kb,
              const float* __restrict__ vb,
              bf16_t* __restrict__ Qb, bf16_t* __restrict__ Kb,
              bf16_t* __restrict__ Vt)
{
    __shared__ bf16_t lsA[128 * 64];   // 16 KB
    __shared__ bf16_t lsB[128 * 64];   // 16 KB

    const int tid  = threadIdx.x;
    const int lane = tid & 63;
    const int w    = tid >> 6;
    const int wm   = w & 1, wn = w >> 1;
    const int ll   = lane & 15;
    const int quad = lane >> 4;

    const int m0 = blockIdx.y * 128;
    const int n0 = blockIdx.x * 128;
    const int z  = blockIdx.z;

    const bf16_t* A = Xb;
    const bf16_t* B = Wb + z * 262144;

    f32x4 acc[4][4];
#pragma unroll
    for (int i = 0; i < 4; i++)
#pragma unroll
        for (int j = 0; j < 4; j++) acc[i][j] = (f32x4){0.f, 0.f, 0.f, 0.f};

    for (int k0 = 0; k0 < 512; k0 += 64) {
#pragma unroll
        for (int c = 0; c < 4; ++c) {
            const int base = (c * 4 + w) * 64;
            const int slot = base + lane;
            const int row  = slot >> 3;
            const int kc   = ((slot & 7) ^ (row & 7)) << 3;
            lds_dma16(A + (size_t)(m0 + row) * 512 + k0 + kc, (char*)lsA + base * 16);
            lds_dma16(B + (size_t)(n0 + row) * 512 + k0 + kc, (char*)lsB + base * 16);
        }
        __syncthreads();

#pragma unroll
        for (int t = 0; t < 2; t++) {
            short8 af[4], bf[4];
#pragma unroll
            for (int i = 0; i < 4; i++) {
                const int ri = wm * 64 + i * 16 + ll;
                const int rj = wn * 64 + i * 16 + ll;
                af[i] = *(const short8*)(lsA + ri * 64 + (((t * 4 + quad) ^ (ll & 7)) << 3));
                bf[i] = *(const short8*)(lsB + rj * 64 + (((t * 4 + quad) ^ (ll & 7)) << 3));
            }
#pragma unroll
            for (int i = 0; i < 4; i++)
#pragma unroll
                for (int j = 0; j < 4; j++)
                    acc[i][j] = __builtin_amdgcn_mfma_f32_16x16x32_bf16(af[i], bf[j], acc[i][j], 0, 0, 0);
        }
        __syncthreads();
    }

    const float inv = 0.044194173824159216f;  // 1/sqrt(512)
#pragma unroll
    for (int i = 0; i < 4; i++) {
#pragma unroll
        for (int j = 0; j < 4; j++) {
            const int col  = n0 + wn * 64 + j * 16 + ll;
            const int rowb = m0 + wm * 64 + i * 16 + quad * 4;
            f32x4 a = acc[i][j];
            if (z == 0) {
                const float bv = qb[col];
#pragma unroll
                for (int r = 0; r < 4; r++)
                    Qb[(size_t)(rowb + r) * 512 + col] = f2b((a[r] + bv) * inv);
            } else if (z == 1) {
                const float bv = kb[col];
#pragma unroll
                for (int r = 0; r < 4; r++)
                    Kb[(size_t)(rowb + r) * 512 + col] = f2b(a[r] + bv);
            } else {  // V, transposed store Vt[b][col][s]
                const float bv = vb[col];
                const int b = rowb >> 12;
                const int s = rowb & 4095;
                ushort4 pk;
                pk.x = f2b(a[0] + bv);
                pk.y = f2b(a[1] + bv);
                pk.z = f2b(a[2] + bv);
                pk.w = f2b(a[3] + bv);
                *(ushort4*)(Vt + ((size_t)b * 512 + col) * 4096 + s) = pk;
            }
        }
    }
}

// ---------- scores: P = sigmoid(Q K^T + bias), BK=64, supertile swizzle ----------
// grid.x = 4096 flat: batch fastest (bias tile shared), then 4m x 8n supertiles.
__global__ __launch_bounds__(256)
void scores_sig(const bf16_t* __restrict__ Qb, const bf16_t* __restrict__ Kb,
                const float* __restrict__ bias, bf16_t* __restrict__ P)
{
    __shared__ bf16_t lsA[128 * 64];
    __shared__ bf16_t lsB[128 * 64];

    const int tid  = threadIdx.x;
    const int lane = tid & 63;
    const int w    = tid >> 6;
    const int wm   = w & 1, wn = w >> 1;
    const int ll   = lane & 15;
    const int quad = lane >> 4;

    const int bx  = blockIdx.x;
    const int z   = bx & 3;
    const int t_  = bx >> 2;              // 0..1023
    const int sup = t_ >> 5;              // 32 supertiles (8 in m x 4 in n)
    const int win = t_ & 31;              // 32 tiles per supertile (4m x 8n)
    const int m0  = ((sup >> 2) * 4 + (win & 3)) * 128;
    const int n0  = ((sup & 3) * 8 + (win >> 2)) * 128;

    const bf16_t* A = Qb + (size_t)z * 2097152;
    const bf16_t* B = Kb + (size_t)z * 2097152;
    bf16_t* out = P + (size_t)z * 16777216;

    f32x4 acc[4][4];
#pragma unroll
    for (int i = 0; i < 4; i++)
#pragma unroll
        for (int j = 0; j < 4; j++) acc[i][j] = (f32x4){0.f, 0.f, 0.f, 0.f};

    for (int k0 = 0; k0 < 512; k0 += 64) {
#pragma unroll
        for (int c = 0; c < 4; ++c) {
            const int base = (c * 4 + w) * 64;
            const int slot = base + lane;
            const int row  = slot >> 3;
            const int kc   = ((slot & 7) ^ (row & 7)) << 3;
            lds_dma16(A + (size_t)(m0 + row) * 512 + k0 + kc, (char*)lsA + base * 16);
            lds_dma16(B + (size_t)(n0 + row) * 512 + k0 + kc, (char*)lsB + base * 16);
        }
        __syncthreads();

#pragma unroll
        for (int t = 0; t < 2; t++) {
            short8 af[4], bf[4];
#pragma unroll
            for (int i = 0; i < 4; i++) {
                const int ri = wm * 64 + i * 16 + ll;
                const int rj = wn * 64 + i * 16 + ll;
                af[i] = *(const short8*)(lsA + ri * 64 + (((t * 4 + quad) ^ (ll & 7)) << 3));
                bf[i] = *(const short8*)(lsB + rj * 64 + (((t * 4 + quad) ^ (ll & 7)) << 3));
            }
#pragma unroll
            for (int i = 0; i < 4; i++)
#pragma unroll
                for (int j = 0; j < 4; j++)
                    acc[i][j] = __builtin_amdgcn_mfma_f32_16x16x32_bf16(af[i], bf[j], acc[i][j], 0, 0, 0);
        }
        __syncthreads();
    }

    // cheap sigmoid epilogue: fp32 bias (shared by 4 batch-siblings), truncated pack
#pragma unroll
    for (int i = 0; i < 4; i++) {
#pragma unroll
        for (int j = 0; j < 4; j++) {
            const int col  = n0 + wn * 64 + j * 16 + ll;
            const int rowb = m0 + wm * 64 + i * 16 + quad * 4;
            f32x4 a = acc[i][j];
#pragma unroll
            for (int r = 0; r < 4; r++) {
                const int row = rowb + r;
                const float v = a[r] + bias[(size_t)row * 4096 + col];
                const float p = __builtin_amdgcn_rcpf(1.f + __expf(-v));
                out[(size_t)row * 4096 + col] = (bf16_t)(__float_as_uint(p) >> 16);
            }
        }
    }
}

// ---------- PV: out = P * Vt^T, BM=64 BN=256, BK=64 ----------
__global__ __launch_bounds__(256)
void pv_gemm(const bf16_t* __restrict__ P, const bf16_t* __restrict__ Vt,
             float* __restrict__ outg)
{
    __shared__ bf16_t lsA[64 * 64];    // 8 KB
    __shared__ bf16_t lsB[256 * 64];   // 32 KB

    const int tid  = threadIdx.x;
    const int lane = tid & 63;
    const int w    = tid >> 6;
    const int wn   = w;            // 0..3: 64-col group
    const int ll   = lane & 15;
    const int quad = lane >> 4;

    const int n0 = blockIdx.x * 256;
    const int m0 = blockIdx.y * 64;
    const int z  = blockIdx.z;

    const bf16_t* A = P + (size_t)z * 16777216;   // [4096][4096]
    const bf16_t* B = Vt + (size_t)z * 2097152;   // [512][4096]
    float* out = outg + (size_t)z * 2097152;

    f32x4 acc[4][4];
#pragma unroll
    for (int i = 0; i < 4; i++)
#pragma unroll
        for (int j = 0; j < 4; j++) acc[i][j] = (f32x4){0.f, 0.f, 0.f, 0.f};

    for (int k0 = 0; k0 < 4096; k0 += 64) {
        // A: 64x8 = 512 chunks (2 rounds); B: 256x8 = 2048 chunks (8 rounds)
#pragma unroll
        for (int c = 0; c < 2; ++c) {
            const int base = (c * 4 + w) * 64;
            const int slot = base + lane;
            const int row  = slot >> 3;
            const int kc   = ((slot & 7) ^ (row & 7)) << 3;
            lds_dma16(A + (size_t)(m0 + row) * 4096 + k0 + kc, (char*)lsA + base * 16);
        }
#pragma unroll
        for (int c = 0; c < 8; ++c) {
            const int base = (c * 4 + w) * 64;
            const int slot = base + lane;
            const int row  = slot >> 3;
            const int kc   = ((slot & 7) ^ (row & 7)) << 3;
            lds_dma16(B + (size_t)(n0 + row) * 4096 + k0 + kc, (char*)lsB + base * 16);
        }
        __syncthreads();

#pragma unroll
        for (int t = 0; t < 2; t++) {
            short8 af[4], bf[4];
#pragma unroll
            for (int i = 0; i < 4; i++) {
                const int ri = i * 16 + ll;
                const int rj = wn * 64 + i * 16 + ll;
                af[i] = *(const short8*)(lsA + ri * 64 + (((t * 4 + quad) ^ (ll & 7)) << 3));
                bf[i] = *(const short8*)(lsB + rj * 64 + (((t * 4 + quad) ^ (ll & 7)) << 3));
            }
#pragma unroll
            for (int i = 0; i < 4; i++)
#pragma unroll
                for (int j = 0; j < 4; j++)
                    acc[i][j] = __builtin_amdgcn_mfma_f32_16x16x32_bf16(af[i], bf[j], acc[i][j], 0, 0, 0);
        }
        __syncthreads();
    }

#pragma unroll
    for (int i = 0; i < 4; i++) {
#pragma unroll
        for (int j = 0; j < 4; j++) {
            const int col  = n0 + wn * 64 + j * 16 + ll;
            const int rowb = m0 + i * 16 + quad * 4;
            f32x4 a = acc[i][j];
#pragma unroll
            for (int r = 0; r < 4; r++)
                out[(size_t)(rowb + r) * 512 + col] = a[r];
        }
    }
}

extern "C" void kernel_launch(void* const* d_in, const int* in_sizes, int n_in,
                              void* d_out, int out_size, void* d_ws, size_t ws_size,
                              hipStream_t stream) {
    (void)in_sizes; (void)n_in; (void)out_size; (void)ws_size;
    const float* x    = (const float*)d_in[0];
    const float* bias = (const float*)d_in[1];
    const float* Wq_w = (const float*)d_in[2];
    const float* Wq_b = (const float*)d_in[3];
    const float* Wk_w = (const float*)d_in[4];
    const float* Wk_b = (const float*)d_in[5];
    const float* Wv_w = (const float*)d_in[6];
    const float* Wv_b = (const float*)d_in[7];
    float* out = (float*)d_out;

    // workspace layout (bf16 elements)
    bf16_t* Xb = (bf16_t*)d_ws;                    // 16384 x 512
    bf16_t* Wb = Xb + (size_t)16384 * 512;         // 3 x 512 x 512
    bf16_t* Qb = Wb + (size_t)3 * 512 * 512;       // 16384 x 512 (pre-scaled 1/sqrt(D))
    bf16_t* Kb = Qb + (size_t)16384 * 512;         // 16384 x 512
    bf16_t* Vt = Kb + (size_t)16384 * 512;         // 4 x 512 x 4096 (transposed V)
    bf16_t* P  = Vt + (size_t)16384 * 512;         // 4 x 4096 x 4096

    cvt_f32_bf16<<<8192, 256, 0, stream>>>(x, Xb, 2097152);
    cvt_w3<<<768, 256, 0, stream>>>(Wq_w, Wk_w, Wv_w, Wb);

    // all three projections in one launch
    proj_all<<<dim3(4, 128, 3), 256, 0, stream>>>(Xb, Wb, Wq_b, Wk_b, Wv_b,
                                                  Qb, Kb, Vt);
    // scores + sigmoid; flat grid w/ batch-fastest + 4m x 8n supertile swizzle
    scores_sig<<<4096, 256, 0, stream>>>(Qb, Kb, bias, P);
    // out = P * V, 64x256 tiles, BK=64
    pv_gemm<<<dim3(2, 64, 4), 256, 0, stream>>>(P, Vt, out);
}